// Round 7
// baseline (301.555 us; speedup 1.0000x reference)
//
#include <hip/hip_runtime.h>

#define CUR 512
#define FULLS 1024
#define BSZ 8
#define DIMM 1024
#define NH 16
#define HD 64

typedef __attribute__((ext_vector_type(8))) short short8;
typedef __attribute__((ext_vector_type(4))) float floatx4;

__device__ __forceinline__ unsigned short f2bf(float x) {
  unsigned int u = __float_as_uint(x);
  unsigned int r = (u + 0x7fffu + ((u >> 16) & 1u)) >> 16;
  return (unsigned short)r;
}
__device__ __forceinline__ float bf2f(unsigned short h) {
  return __uint_as_float(((unsigned int)h) << 16);
}

__device__ __forceinline__ void async16(void* lds, const void* g) {
  __builtin_amdgcn_global_load_lds(
      (const __attribute__((address_space(1))) unsigned int*)g,
      (__attribute__((address_space(3))) unsigned int*)lds, 16, 0, 0);
}

// ---------------------------------------------------------------------------
// Fused prep: all fp32->bf16 casts + weight transpose-casts in ONE launch.
// Also zeroes the work-steal counter (lives in d_out, used by proj_gemm).
// ---------------------------------------------------------------------------
__global__ __launch_bounds__(256)
void prep_kernel(const float* __restrict__ fi, short* __restrict__ fi_bf,
                 const float* __restrict__ inp, short* __restrict__ in_bf,
                 const float* __restrict__ pe, short* __restrict__ pe_bf,
                 const float* __restrict__ Wkv, short* __restrict__ Wkv_t,
                 const float* __restrict__ Wq, short* __restrict__ Wq_t,
                 const float* __restrict__ Wpos, short* __restrict__ Wpos_t,
                 const float* __restrict__ Wproj, short* __restrict__ Wproj_t,
                 int* __restrict__ counter) {
  __shared__ float t[64][65];
  const int blk = blockIdx.x;
  const int tid = threadIdx.x;
  if (blk == 0 && tid == 0) *counter = 0;
  if (blk < 6656) {
    const float* x; short* y; int base;
    if (blk < 4096)      { x = fi;  y = fi_bf; base = blk; }
    else if (blk < 6144) { x = inp; y = in_bf; base = blk - 4096; }
    else                 { x = pe;  y = pe_bf; base = blk - 6144; }
    int i = (base * 256 + tid) * 8;
    float a[8];
    *(float4*)&a[0] = *(const float4*)&x[i];
    *(float4*)&a[4] = *(const float4*)&x[i + 4];
    short8 o;
    #pragma unroll
    for (int j = 0; j < 8; ++j) o[j] = f2bf(a[j]);
    *(short8*)&y[i] = o;
    return;
  }
  const float* W; short* Wt; int N, t2;
  if (blk < 7168)      { W = Wkv;   Wt = Wkv_t;   N = 2048; t2 = blk - 6656; }
  else if (blk < 7424) { W = Wq;    Wt = Wq_t;    N = 1024; t2 = blk - 7168; }
  else if (blk < 7680) { W = Wpos;  Wt = Wpos_t;  N = 1024; t2 = blk - 7424; }
  else                 { W = Wproj; Wt = Wproj_t; N = 1024; t2 = blk - 7680; }
  const int K = 1024;
  const int nx = N / 64;
  const int n0 = (t2 % nx) * 64, k0 = (t2 / nx) * 64;
  #pragma unroll
  for (int r = 0; r < 4; ++r) {
    int f = tid + r * 256;
    int row = f >> 4, c = (f & 15) * 4;
    float4 v = *(const float4*)&W[(size_t)(k0 + row) * N + n0 + c];
    t[c + 0][row] = v.x; t[c + 1][row] = v.y;
    t[c + 2][row] = v.z; t[c + 3][row] = v.w;
  }
  __syncthreads();
  #pragma unroll
  for (int r = 0; r < 2; ++r) {
    int f = tid + r * 256;
    int row = f >> 3, c = (f & 7) * 8;
    short8 o;
    #pragma unroll
    for (int j = 0; j < 8; ++j) o[j] = f2bf(t[row][c + j]);
    *(short8*)&Wt[(size_t)(n0 + row) * K + k0 + c] = o;
  }
}

// ---------------------------------------------------------------------------
// bf16 MFMA GEMM body: C[M,N] = A[M,K] @ Bt[N,K]^T + bias. 128x128 tile.
// ---------------------------------------------------------------------------
__device__ __forceinline__
void gemm_body(short* As, short* Bs,
               const short* __restrict__ A, const short* __restrict__ Bt,
               const float* __restrict__ bias, void* __restrict__ Cp,
               int M, int N, int K, int out_bf16, int bx, int by) {
  const int tid = threadIdx.x;
  const int w = tid >> 6, lane = tid & 63, l15 = lane & 15, quad = lane >> 4;
  const int m0 = by * 128, n0 = bx * 128;
  const int wm = (w & 1) * 64, wn = (w >> 1) * 64;

  floatx4 acc[4][4];
  #pragma unroll
  for (int i = 0; i < 4; ++i)
    #pragma unroll
    for (int j = 0; j < 4; ++j) acc[i][j] = (floatx4){0.f, 0.f, 0.f, 0.f};

  for (int k0 = 0; k0 < K; k0 += 32) {
    __syncthreads();
    #pragma unroll
    for (int rnd = 0; rnd < 2; ++rnd) {
      int fb = rnd * 256 + w * 64;
      int f = fb + lane;
      int row = f >> 2, c = f & 3;
      int cs = (c ^ (row & 3)) * 8;
      async16(As + fb * 8, &A[(size_t)(m0 + row) * K + k0 + cs]);
      async16(Bs + fb * 8, &Bt[(size_t)(n0 + row) * K + k0 + cs]);
    }
    __syncthreads();
    short8 af[4], bf[4];
    #pragma unroll
    for (int t = 0; t < 4; ++t) {
      int swz = ((quad ^ (l15 & 3)) * 8);
      af[t] = *(const short8*)&As[(wm + t * 16 + l15) * 32 + swz];
      bf[t] = *(const short8*)&Bs[(wn + t * 16 + l15) * 32 + swz];
    }
    #pragma unroll
    for (int mt = 0; mt < 4; ++mt)
      #pragma unroll
      for (int nt = 0; nt < 4; ++nt)
        acc[mt][nt] = __builtin_amdgcn_mfma_f32_16x16x32_bf16(
            af[mt], bf[nt], acc[mt][nt], 0, 0, 0);
  }

  #pragma unroll
  for (int mt = 0; mt < 4; ++mt)
    #pragma unroll
    for (int nt = 0; nt < 4; ++nt)
      #pragma unroll
      for (int r = 0; r < 4; ++r) {
        int row = m0 + wm + mt * 16 + quad * 4 + r;
        int col = n0 + wn + nt * 16 + l15;
        float v = acc[mt][nt][r] + bias[col];
        if (out_bf16) ((short*)Cp)[(size_t)row * N + col] = (short)f2bf(v);
        else          ((float*)Cp)[(size_t)row * N + col] = v;
      }
}

// ---------------------------------------------------------------------------
// Persistent fused input projections with dynamic work-stealing.
// Tiles: 0..1023 kv (16x64), 1024..1279 q (8x32), 1280..1343 r (8x8).
// 512 blocks (2/CU); each steals tiles from the atomic counter until empty.
// ---------------------------------------------------------------------------
__global__ __launch_bounds__(256)
void proj_gemm_kernel(const short* __restrict__ fi_bf, const short* __restrict__ Wkv_t,
                      const float* __restrict__ b_kv, short* __restrict__ kv_bf,
                      const short* __restrict__ in_bf, const short* __restrict__ Wq_t,
                      const float* __restrict__ b_q, float* __restrict__ q_f32,
                      const short* __restrict__ pe_bf, const short* __restrict__ Wpos_t,
                      const float* __restrict__ b_pos, short* __restrict__ r_bf,
                      int* __restrict__ counter) {
  __shared__ short As[128 * 32];
  __shared__ short Bs[128 * 32];
  __shared__ int s_tile;
  const int tid = threadIdx.x;
  for (;;) {
    if (tid == 0) s_tile = atomicAdd(counter, 1);
    __syncthreads();
    const int blk = s_tile;
    if (blk >= 1344) break;
    if (blk < 1024)
      gemm_body(As, Bs, fi_bf, Wkv_t, b_kv, kv_bf, 8192, 2048, 1024, 1,
                blk % 16, blk / 16);
    else if (blk < 1280) {
      int tb = blk - 1024;
      gemm_body(As, Bs, in_bf, Wq_t, b_q, q_f32, 4096, 1024, 1024, 0,
                tb % 8, tb / 8);
    } else {
      int tb = blk - 1280;
      gemm_body(As, Bs, pe_bf, Wpos_t, b_pos, r_bf, 1024, 1024, 1024, 1,
                tb % 8, tb / 8);
    }
    __syncthreads();
  }
}

// ---------------------------------------------------------------------------
// Output projection: 64x128 tiles, 512 blocks (2/CU, 8 waves/CU).
// Wave w: rows (w&1)*32..+31, cols (w>>1)*64..+63 -> acc[2][4].
// ---------------------------------------------------------------------------
__global__ __launch_bounds__(256)
void out_gemm_kernel(const short* __restrict__ av_bf, const short* __restrict__ Wproj_t,
                     const float* __restrict__ b_proj, float* __restrict__ out) {
  __shared__ short As[64 * 32];
  __shared__ short Bs[128 * 32];
  const int tid = threadIdx.x;
  const int w = tid >> 6, lane = tid & 63, l15 = lane & 15, quad = lane >> 4;
  const int m0 = (blockIdx.x >> 3) * 64, n0 = (blockIdx.x & 7) * 128;
  const int wm = (w & 1) * 32, wn = (w >> 1) * 64;
  const int N = 1024, K = 1024;

  floatx4 acc[2][4];
  #pragma unroll
  for (int i = 0; i < 2; ++i)
    #pragma unroll
    for (int j = 0; j < 4; ++j) acc[i][j] = (floatx4){0.f, 0.f, 0.f, 0.f};

  for (int k0 = 0; k0 < K; k0 += 32) {
    __syncthreads();
    {
      // A tile 64x32: one 256-lane round
      int f = w * 64 + lane;
      int row = f >> 2, c = f & 3;
      int cs = (c ^ (row & 3)) * 8;
      async16(As + f * 8, &av_bf[(size_t)(m0 + row) * K + k0 + cs]);
      // B tile 128x32: two rounds
      #pragma unroll
      for (int rnd = 0; rnd < 2; ++rnd) {
        int fb = rnd * 256 + w * 64;
        int f2 = fb + lane;
        int row2 = f2 >> 2, c2 = f2 & 3;
        int cs2 = (c2 ^ (row2 & 3)) * 8;
        async16(Bs + fb * 8, &Wproj_t[(size_t)(n0 + row2) * K + k0 + cs2]);
      }
    }
    __syncthreads();
    short8 af[2], bf[4];
    #pragma unroll
    for (int t = 0; t < 2; ++t) {
      int swz = ((quad ^ (l15 & 3)) * 8);
      af[t] = *(const short8*)&As[(wm + t * 16 + l15) * 32 + swz];
    }
    #pragma unroll
    for (int t = 0; t < 4; ++t) {
      int swz = ((quad ^ (l15 & 3)) * 8);
      bf[t] = *(const short8*)&Bs[(wn + t * 16 + l15) * 32 + swz];
    }
    #pragma unroll
    for (int mt = 0; mt < 2; ++mt)
      #pragma unroll
      for (int nt = 0; nt < 4; ++nt)
        acc[mt][nt] = __builtin_amdgcn_mfma_f32_16x16x32_bf16(
            af[mt], bf[nt], acc[mt][nt], 0, 0, 0);
  }

  #pragma unroll
  for (int mt = 0; mt < 2; ++mt)
    #pragma unroll
    for (int nt = 0; nt < 4; ++nt)
      #pragma unroll
      for (int r = 0; r < 4; ++r) {
        int row = m0 + wm + mt * 16 + quad * 4 + r;
        int col = n0 + wn + nt * 16 + l15;
        out[(size_t)row * N + col] = acc[mt][nt][r] + b_proj[col];
      }
}

// ---------------------------------------------------------------------------
// Pipelined MFMA flash attention (unchanged from R6).
// ---------------------------------------------------------------------------
__global__ __launch_bounds__(256, 2)
void attn_mfma_kernel(const float* __restrict__ qf, const short* __restrict__ kvb,
                      const short* __restrict__ rb, const float* __restrict__ um,
                      const float* __restrict__ vm, short* __restrict__ avb) {
  const int h = blockIdx.x, qt = blockIdx.y, b = blockIdx.z;
  const int tid = threadIdx.x;
  const int w = tid >> 6, lane = tid & 63, l15 = lane & 15, quad = lane >> 4;
  const float SCL2E = 0.125f * 1.44269504089f;

  __shared__ short Ks[2][64 * 64];
  __shared__ short Rs[2][64 * 64];
  __shared__ unsigned int Vt[2][64 * 32];
  __shared__ short Pb[2][64 * 69];
  __shared__ short Pt[4][16 * 72];

  const int jtmax = qt + 8;

  short8 qu_[2], qv_[2];
  {
    int qrow = qt * 64 + w * 16 + l15;
    size_t gbase = ((size_t)qrow * BSZ + b) * 1024 + h * 64;
    #pragma unroll
    for (int ks = 0; ks < 2; ++ks) {
      int d0 = ks * 32 + quad * 8;
      float qa[8], ua[8], va[8];
      *(float4*)&qa[0] = *(const float4*)&qf[gbase + d0];
      *(float4*)&qa[4] = *(const float4*)&qf[gbase + d0 + 4];
      *(float4*)&ua[0] = *(const float4*)&um[h * 64 + d0];
      *(float4*)&ua[4] = *(const float4*)&um[h * 64 + d0 + 4];
      *(float4*)&va[0] = *(const float4*)&vm[h * 64 + d0];
      *(float4*)&va[4] = *(const float4*)&vm[h * 64 + d0 + 4];
      #pragma unroll
      for (int j = 0; j < 8; ++j) {
        qu_[ks][j] = f2bf((qa[j] + ua[j]) * SCL2E);
        qv_[ks][j] = f2bf((qa[j] + va[j]) * SCL2E);
      }
    }
  }

  auto stage_K = [&](int buf, int jt) {
    #pragma unroll
    for (int rnd = 0; rnd < 2; ++rnd) {
      int fb = rnd * 256 + w * 64;
      int f = fb + lane;
      int row = f >> 3, c = f & 7;
      int cs = (c ^ (row & 7)) * 8;
      async16(&Ks[buf][fb * 8],
              &kvb[((size_t)(jt * 64 + row) * BSZ + b) * 2048 + h * 64 + cs]);
    }
  };
  auto stage_R = [&](int buf, int p0) {
    #pragma unroll
    for (int rnd = 0; rnd < 2; ++rnd) {
      int fb = rnd * 256 + w * 64;
      int f = fb + lane;
      int row = f >> 3, c = f & 7;
      int cs = (c ^ (row & 7)) * 8;
      async16(&Rs[buf][fb * 8], &rb[(size_t)(p0 + row) * 1024 + h * 64 + cs]);
    }
  };
  const int dc = tid & 7, kp = tid >> 3;
  auto loadV = [&](int jt, short8* va, short8* vb) {
    size_t g0 = ((size_t)(jt * 64 + kp * 2) * BSZ + b) * 2048 + 1024 + h * 64 + dc * 8;
    *va = *(const short8*)&kvb[g0];
    *vb = *(const short8*)&kvb[g0 + 2048 * BSZ];
  };
  auto packV = [&](int buf, short8 va, short8 vb) {
    #pragma unroll
    for (int i = 0; i < 8; ++i) {
      int d = dc * 8 + i;
      int swz = (i ^ dc) & 7;
      Vt[buf][d * 32 + (((kp >> 2) ^ swz) * 4) + (kp & 3)] =
          (unsigned int)(unsigned short)va[i] |
          ((unsigned int)(unsigned short)vb[i] << 16);
    }
  };
  auto compute_chunk = [&](int buf, int rbuf) {
    #pragma unroll
    for (int nt = 0; nt < 4; ++nt) {
      floatx4 a = (floatx4){0.f, 0.f, 0.f, 0.f};
      #pragma unroll
      for (int ks = 0; ks < 2; ++ks) {
        short8 bfr = *(const short8*)
            &Rs[rbuf][(nt * 16 + l15) * 64 + (((ks * 4 + quad) ^ (l15 & 7)) * 8)];
        a = __builtin_amdgcn_mfma_f32_16x16x32_bf16(qv_[ks], bfr, a, 0, 0, 0);
      }
      #pragma unroll
      for (int r = 0; r < 4; ++r)
        Pb[buf][(w * 16 + quad * 4 + r) * 69 + nt * 16 + l15] = (short)f2bf(a[r]);
    }
  };

  stage_K(0, 0);
  stage_R(0, 448 - qt * 64);
  stage_R(1, 512 - qt * 64);
  short8 vra, vrb;
  loadV(0, &vra, &vrb);
  packV(0, vra, vrb);
  __syncthreads();

  compute_chunk(1, 0);

  float lsum[4];
  floatx4 O[4];
  #pragma unroll
  for (int r = 0; r < 4; ++r) lsum[r] = 0.f;
  #pragma unroll
  for (int nt = 0; nt < 4; ++nt) O[nt] = (floatx4){0.f, 0.f, 0.f, 0.f};

  for (int jt = 0; jt <= jtmax; ++jt) {
    const int cur = jt & 1, nxt = cur ^ 1;

    if (jt < jtmax) {
      stage_K(nxt, jt + 1);
      loadV(jt + 1, &vra, &vrb);
    }
    if (jt + 1 < jtmax) stage_R(cur, 512 + 64 * (jt + 1 - qt));

    if (jt < jtmax) compute_chunk(cur, nxt);

    floatx4 S[4];
    #pragma unroll
    for (int nt = 0; nt < 4; ++nt) {
      S[nt] = (floatx4){0.f, 0.f, 0.f, 0.f};
      #pragma unroll
      for (int ks = 0; ks < 2; ++ks) {
        short8 bfr = *(const short8*)
            &Ks[cur][(nt * 16 + l15) * 64 + (((ks * 4 + quad) ^ (l15 & 7)) * 8)];
        S[nt] = __builtin_amdgcn_mfma_f32_16x16x32_bf16(qu_[ks], bfr, S[nt], 0, 0, 0);
      }
    }

    #pragma unroll
    for (int nt = 0; nt < 4; ++nt) {
      #pragma unroll
      for (int r = 0; r < 4; ++r) {
        int il = w * 16 + quad * 4 + r;
        int jl = nt * 16 + l15;
        int rel = jl - il + 63;
        float pos = (rel >= 64) ? bf2f((unsigned short)Pb[cur][il * 69 + rel - 64])
                                : bf2f((unsigned short)Pb[nxt][il * 69 + rel]);
        float z = S[nt][r] + pos;
        if (jt == jtmax && jl > il) z = -1e30f;
        float e = __builtin_amdgcn_exp2f(z);
        S[nt][r] = e;
        lsum[r] += e;
      }
    }

    #pragma unroll
    for (int nt = 0; nt < 4; ++nt)
      #pragma unroll
      for (int r = 0; r < 4; ++r)
        Pt[w][(quad * 4 + r) * 72 + nt * 16 + l15] = (short)f2bf(S[nt][r]);

    short8 pf[2];
    #pragma unroll
    for (int ks = 0; ks < 2; ++ks)
      pf[ks] = *(const short8*)&Pt[w][l15 * 72 + ks * 32 + quad * 8];

    #pragma unroll
    for (int ntd = 0; ntd < 4; ++ntd) {
      int d = ntd * 16 + l15;
      int swv = (d ^ (d >> 3)) & 7;
      #pragma unroll
      for (int ks = 0; ks < 2; ++ks) {
        short8 vfr = *(const short8*)&Vt[cur][d * 32 + (((ks * 4 + quad) ^ swv) * 4)];
        O[ntd] = __builtin_amdgcn_mfma_f32_16x16x32_bf16(pf[ks], vfr, O[ntd], 0, 0, 0);
      }
    }

    if (jt < jtmax) packV(nxt, vra, vrb);

    __syncthreads();
  }

  #pragma unroll
  for (int r = 0; r < 4; ++r) {
    float rs = lsum[r];
    rs += __shfl_xor(rs, 1);
    rs += __shfl_xor(rs, 2);
    rs += __shfl_xor(rs, 4);
    rs += __shfl_xor(rs, 8);
    float inv = 1.f / rs;
    int qrow = qt * 64 + w * 16 + quad * 4 + r;
    size_t gb = ((size_t)qrow * BSZ + b) * 1024 + h * 64;
    #pragma unroll
    for (int ntd = 0; ntd < 4; ++ntd)
      avb[gb + ntd * 16 + l15] = (short)f2bf(O[ntd][r] * inv);
  }
}

// ---------------------------------------------------------------------------
extern "C" void kernel_launch(void* const* d_in, const int* in_sizes, int n_in,
                              void* d_out, int out_size, void* d_ws, size_t ws_size,
                              hipStream_t stream) {
  const float* inputs  = (const float*)d_in[0];
  const float* pos_emb = (const float*)d_in[1];
  const float* full_in = (const float*)d_in[2];
  const float* u       = (const float*)d_in[3];
  const float* v       = (const float*)d_in[4];
  const float* W_kv    = (const float*)d_in[6];
  const float* b_kv    = (const float*)d_in[7];
  const float* W_q     = (const float*)d_in[8];
  const float* b_q     = (const float*)d_in[9];
  const float* W_pos   = (const float*)d_in[10];
  const float* b_pos   = (const float*)d_in[11];
  const float* W_proj  = (const float*)d_in[12];
  const float* b_proj  = (const float*)d_in[13];
  float* out = (float*)d_out;

  char* ws = (char*)d_ws;
  short* fi_bf   = (short*)(ws + 0);          // 8192x1024 bf16  16 MB
  short* in_bf   = (short*)(ws + 16777216);   // 4096x1024 bf16   8 MB
  short* pe_bf   = (short*)(ws + 25165824);   // 1024x1024 bf16   2 MB
  short* Wkv_t   = (short*)(ws + 27262976);   // 2048x1024 bf16   4 MB
  short* Wq_t    = (short*)(ws + 31457280);   // 1024x1024 bf16   2 MB
  short* Wpos_t  = (short*)(ws + 33554432);   // 1024x1024 bf16   2 MB
  short* Wproj_t = (short*)(ws + 35651584);   // 1024x1024 bf16   2 MB
  short* kv_bf   = (short*)(ws + 37748736);   // 8192x2048 bf16  32 MB
  float* q_f32   = (float*)(ws + 71303168);   // 4096x1024 fp32  16 MB
  short* r_bf    = (short*)(ws + 88080384);   // 1024x1024 bf16   2 MB
  short* av_bf   = (short*)(ws + 90177536);   // 4096x1024 bf16   8 MB

  // work-steal counter lives in d_out (zeroed by prep, consumed by proj,
  // fully overwritten later by out_gemm)
  int* counter = (int*)d_out;

  prep_kernel<<<7936, 256, 0, stream>>>(full_in, fi_bf, inputs, in_bf,
                                        pos_emb, pe_bf, W_kv, Wkv_t, W_q, Wq_t,
                                        W_pos, Wpos_t, W_proj, Wproj_t, counter);

  proj_gemm_kernel<<<512, 256, 0, stream>>>(fi_bf, Wkv_t, b_kv, kv_bf,
                                            in_bf, Wq_t, b_q, q_f32,
                                            pe_bf, Wpos_t, b_pos, r_bf, counter);

  attn_mfma_kernel<<<dim3(NH, 8, BSZ), 256, 0, stream>>>(q_f32, kv_bf, r_bf,
                                                         u, v, av_bf);

  out_gemm_kernel<<<512, 256, 0, stream>>>(av_bf, Wproj_t, b_proj, out);
}